// Round 8
// baseline (805.269 us; speedup 1.0000x reference)
//
#include <hip/hip_runtime.h>
#include <math.h>

#define NF 16
#define EF 8
#define H1D 32
#define H2D 32
#define OD 64
#define PB 256      // partition blocks (must equal k_mscan blockDim)
#define BNODE 256   // nodes per bin
#define SCAN_T 1024

typedef float f32x4 __attribute__((ext_vector_type(4)));

__device__ __forceinline__ float gelu_exact(float t) {
    return 0.5f * t * (1.0f + erff(t * 0.70710678118654752440f));
}

// ======================= bin path (primary) =======================
// pass 1: per-block per-bin counts via LDS (no global atomics)
__global__ __launch_bounds__(256) void k_count(
    const int* __restrict__ ei, int* __restrict__ cnt, int N, int E, int NBIN, int per)
{
    extern __shared__ int lh[];
    int b = blockIdx.x, t = threadIdx.x;
    for (int i = t; i < NBIN; i += 256) lh[i] = 0;
    __syncthreads();
    int lo = b * per, hi = min(lo + per, E);
    for (int e = lo + t; e < hi; e += 256) {
        int dst = ei[(size_t)E + e];
        int src = ei[e];
        if ((unsigned)dst < (unsigned)N && (unsigned)src < (unsigned)N)
            atomicAdd(&lh[dst >> 8], 1);
    }
    __syncthreads();
    for (int i = t; i < NBIN; i += 256) cnt[(size_t)b * NBIN + i] = lh[i];
}

// pass 2: column-wise exclusive scan of cnt[PB][NBIN]; one block per bin
__global__ __launch_bounds__(256) void k_mscan(
    const int* __restrict__ cnt, int* __restrict__ off, int* __restrict__ coltot, int NBIN)
{
    __shared__ int sh[256];
    int bin = blockIdx.x, t = threadIdx.x;
    int v = cnt[(size_t)t * NBIN + bin];
    sh[t] = v;
    __syncthreads();
    for (int o = 1; o < 256; o <<= 1) {
        int u = (t >= o) ? sh[t - o] : 0;
        __syncthreads();
        sh[t] += u;
        __syncthreads();
    }
    off[(size_t)t * NBIN + bin] = sh[t] - v;
    if (t == 255) coltot[bin] = sh[255];
}

// single-block scan (reused for bin bases and msg-tier rowptr)
__global__ __launch_bounds__(SCAN_T) void k_scan(
    const int* __restrict__ count, int* __restrict__ rowptr, int N)
{
    __shared__ int part[SCAN_T];
    int t = threadIdx.x;
    int C = (N + SCAN_T - 1) / SCAN_T;
    int lo = min(t * C, N), hi = min(lo + C, N);
    int s = 0;
    for (int i = lo; i < hi; ++i) s += count[i];
    part[t] = s;
    __syncthreads();
    for (int off = 1; off < SCAN_T; off <<= 1) {
        int v = (t >= off) ? part[t - off] : 0;
        __syncthreads();
        part[t] += v;
        __syncthreads();
    }
    int run = (t == 0) ? 0 : part[t - 1];
    for (int i = lo; i < hi; ++i) { rowptr[i] = run; run += count[i]; }
    if (t == SCAN_T - 1) rowptr[N] = part[SCAN_T - 1];
}

// pass 3: place edge payload into bin-segmented arrays (LDS slot claim)
__global__ __launch_bounds__(256) void k_place(
    const int* __restrict__ ei, const float* __restrict__ ea,
    const int* __restrict__ off, const int* __restrict__ binbase,
    unsigned* __restrict__ srcpk, float* __restrict__ ea8,
    int N, int E, int NBIN, int per)
{
    extern __shared__ int lc[];
    int b = blockIdx.x, t = threadIdx.x;
    for (int i = t; i < NBIN; i += 256) lc[i] = 0;
    __syncthreads();
    int lo = b * per, hi = min(lo + per, E);
    for (int e = lo + t; e < hi; e += 256) {
        int dst = ei[(size_t)E + e];
        int src = ei[e];
        if ((unsigned)dst >= (unsigned)N || (unsigned)src >= (unsigned)N) continue;
        int bin = dst >> 8;
        int pos = atomicAdd(&lc[bin], 1);
        int slot = binbase[bin] + off[(size_t)b * NBIN + bin] + pos;
        srcpk[slot] = ((unsigned)(dst & 255) << 24) | (unsigned)src;
        const f32x4* s4 = reinterpret_cast<const f32x4*>(ea + (size_t)e * EF);
        f32x4 a0 = s4[0], a1 = s4[1];
        f32x4* d4 = reinterpret_cast<f32x4*>(ea8 + (size_t)slot * EF);
        d4[0] = a0; d4[1] = a1;
    }
}

// pass 4: per-bin aggregation in LDS; 2 blocks per bin (split halves)
__global__ __launch_bounds__(256) void k_binagg(
    const float* __restrict__ x, const unsigned* __restrict__ srcpk,
    const float* __restrict__ ea8, const float* __restrict__ We,
    const float* __restrict__ be, const int* __restrict__ binbase,
    float* __restrict__ agg2, int N)
{
    __shared__ float sWe[EF * NF];
    __shared__ float sbe[NF];
    __shared__ float as[NF * BNODE];   // [f][doff] transposed: bank = doff%32
    int t = threadIdx.x;
    int bin = blockIdx.x >> 1, s = blockIdx.x & 1;
    if (t < EF * NF) sWe[t] = We[t];
    if (t < NF) sbe[t] = be[t];
    for (int i = t; i < NF * BNODE; i += 256) as[i] = 0.0f;
    __syncthreads();

    int lo = binbase[bin], hi = binbase[bin + 1];
    int half = (hi - lo) >> 1;
    int l0 = s ? (lo + half) : lo;
    int h0 = s ? hi : (lo + half);

    const f32x4* sw = reinterpret_cast<const f32x4*>(sWe);
    const f32x4* sb4 = reinterpret_cast<const f32x4*>(sbe);
    for (int idx = l0 + t; idx < h0; idx += 256) {
        unsigned u = srcpk[idx];
        int src = (int)(u & 0xFFFFFFu);
        int doff = (int)(u >> 24);
        const f32x4* e4 = reinterpret_cast<const f32x4*>(ea8 + (size_t)idx * EF);
        f32x4 a0 = e4[0], a1 = e4[1];
        float ak[EF] = {a0[0], a0[1], a0[2], a0[3], a1[0], a1[1], a1[2], a1[3]};
        f32x4 ev[4] = {sb4[0], sb4[1], sb4[2], sb4[3]};
#pragma unroll
        for (int k = 0; k < EF; ++k) {
            float a = ak[k];
#pragma unroll
            for (int j = 0; j < 4; ++j) ev[j] += a * sw[k * 4 + j];
        }
        const f32x4* xs = reinterpret_cast<const f32x4*>(x + (size_t)src * NF);
#pragma unroll
        for (int j = 0; j < 4; ++j) {
            f32x4 xv = xs[j];
#pragma unroll
            for (int c = 0; c < 4; ++c) {
                float m = fmaxf(xv[c] + ev[j][c], 0.0f);
                atomicAdd(&as[(j * 4 + c) * BNODE + doff], m);
            }
        }
    }
    __syncthreads();

    float* ag = agg2 + (size_t)s * (size_t)N * NF;
    int node = bin * BNODE + t;          // BNODE == blockDim
    if (t < BNODE && node < N) {
        f32x4* o = reinterpret_cast<f32x4*>(ag + (size_t)node * NF);
#pragma unroll
        for (int j = 0; j < 4; ++j) {
            f32x4 v;
#pragma unroll
            for (int c = 0; c < 4; ++c) v[c] = as[(j * 4 + c) * BNODE + t];
            o[j] = v;
        }
    }
}

// ======================= msg-tier fallback (round-7 proven) =======================
__global__ __launch_bounds__(256) void k_histp(
    const int* __restrict__ ei, int* __restrict__ count, unsigned* __restrict__ packed,
    int N, int E)
{
    int e = blockIdx.x * 256 + threadIdx.x;
    if (e >= E) return;
    int dst = ei[(size_t)E + e];
    if ((unsigned)dst >= (unsigned)N || dst >= (1 << 20)) { packed[e] = 0xFFFFFFFFu; return; }
    int p = atomicAdd(&count[dst], 1);
    if (p > 4095) p = 4095;
    packed[e] = ((unsigned)p << 20) | (unsigned)dst;
}

__global__ __launch_bounds__(256) void k_scatmsg(
    const float* __restrict__ x, const int* __restrict__ ei,
    const float* __restrict__ ea, const float* __restrict__ We,
    const float* __restrict__ be, const int* __restrict__ rowptr,
    const unsigned* __restrict__ packed, float* __restrict__ msg, int N, int E)
{
    __shared__ float sWe[EF * NF];
    __shared__ float sbe[NF];
    int t = threadIdx.x;
    if (t < EF * NF) sWe[t] = We[t];
    if (t < NF) sbe[t] = be[t];
    __syncthreads();

    int e = blockIdx.x * 256 + t;
    if (e >= E) return;
    unsigned u = packed[e];
    if (u == 0xFFFFFFFFu) return;
    int dst = (int)(u & 0xFFFFFu);
    int p   = (int)(u >> 20);
    size_t slot = (size_t)rowptr[dst] + p;
    f32x4* mo = reinterpret_cast<f32x4*>(msg + slot * NF);

    int src = ei[e];
    if ((unsigned)src >= (unsigned)N) {
        f32x4 z = (f32x4)0.0f;
        mo[0] = z; mo[1] = z; mo[2] = z; mo[3] = z;
        return;
    }
    const f32x4* ea4 = reinterpret_cast<const f32x4*>(ea + (size_t)e * EF);
    f32x4 a01 = __builtin_nontemporal_load(ea4 + 0);
    f32x4 a23 = __builtin_nontemporal_load(ea4 + 1);
    float ak[EF] = {a01[0], a01[1], a01[2], a01[3], a23[0], a23[1], a23[2], a23[3]};
    const f32x4* sbe4 = reinterpret_cast<const f32x4*>(sbe);
    f32x4 ev[4] = {sbe4[0], sbe4[1], sbe4[2], sbe4[3]};
    const f32x4* sWe4 = reinterpret_cast<const f32x4*>(sWe);
#pragma unroll
    for (int k = 0; k < EF; ++k) {
        float a = ak[k];
#pragma unroll
        for (int j = 0; j < 4; ++j) ev[j] += a * sWe4[k * 4 + j];
    }
    const f32x4* xs = reinterpret_cast<const f32x4*>(x + (size_t)src * NF);
#pragma unroll
    for (int j = 0; j < 4; ++j) {
        f32x4 xv = xs[j];
        f32x4 m;
#pragma unroll
        for (int c = 0; c < 4; ++c) m[c] = fmaxf(xv[c] + ev[j][c], 0.0f);
        mo[j] = m;
    }
}

__global__ __launch_bounds__(256) void k_gatherseq(
    const int* __restrict__ rowptr, const float* __restrict__ msg,
    float* __restrict__ agg, int N)
{
    int wid = (blockIdx.x * 256 + threadIdx.x) >> 6;
    int lane = threadIdx.x & 63;
    if (wid >= N) return;
    int f = lane & 15, g = lane >> 4;
    int r0 = rowptr[wid], r1 = rowptr[wid + 1];
    float acc = 0.0f;
    for (int t = r0 + g; t < r1; t += 4)
        acc += __builtin_nontemporal_load(msg + (size_t)t * NF + f);
    acc += __shfl_xor(acc, 16);
    acc += __shfl_xor(acc, 32);
    if (g == 0) agg[(size_t)wid * NF + f] = acc;
}

// tier-C last resort
__global__ __launch_bounds__(256) void k_edge(
    const float* __restrict__ x, const int* __restrict__ ei,
    const float* __restrict__ ea, const float* __restrict__ We,
    const float* __restrict__ be, float* __restrict__ agg, int N, int E)
{
    __shared__ float sWe[EF * NF];
    __shared__ float sbe[NF];
    int t = threadIdx.x;
    if (t < EF * NF) sWe[t] = We[t];
    if (t < NF) sbe[t] = be[t];
    __syncthreads();
    int e = blockIdx.x * 256 + t;
    if (e >= E) return;
    int src = ei[e];
    int dst = ei[(size_t)E + e];
    if ((unsigned)src >= (unsigned)N || (unsigned)dst >= (unsigned)N) return;
    const float4* ea4 = reinterpret_cast<const float4*>(ea + (size_t)e * EF);
    float4 a0 = ea4[0], a1 = ea4[1];
    float ak[EF] = {a0.x, a0.y, a0.z, a0.w, a1.x, a1.y, a1.z, a1.w};
    const float4* sbe4 = reinterpret_cast<const float4*>(sbe);
    float4 ev[4] = {sbe4[0], sbe4[1], sbe4[2], sbe4[3]};
    const float4* sWe4 = reinterpret_cast<const float4*>(sWe);
#pragma unroll
    for (int k = 0; k < EF; ++k) {
        float a = ak[k];
#pragma unroll
        for (int j = 0; j < 4; ++j) {
            float4 wv = sWe4[k * 4 + j];
            ev[j].x += a * wv.x; ev[j].y += a * wv.y;
            ev[j].z += a * wv.z; ev[j].w += a * wv.w;
        }
    }
    const float4* xs = reinterpret_cast<const float4*>(x + (size_t)src * NF);
    float* ad = agg + (size_t)dst * NF;
#pragma unroll
    for (int j = 0; j < 4; ++j) {
        float4 xv = xs[j];
        atomicAdd(ad + j * 4 + 0, fmaxf(xv.x + ev[j].x, 0.0f));
        atomicAdd(ad + j * 4 + 1, fmaxf(xv.y + ev[j].y, 0.0f));
        atomicAdd(ad + j * 4 + 2, fmaxf(xv.z + ev[j].z, 0.0f));
        atomicAdd(ad + j * 4 + 3, fmaxf(xv.w + ev[j].w, 0.0f));
    }
}

// ======================= node pipeline =======================
// nodeA sums S agg copies (agg2 layout: [S][N][16]); aggH may be null (S=1)
__global__ __launch_bounds__(256) void k_nodeA(
    const float* __restrict__ x, const float* __restrict__ aggL,
    const float* __restrict__ aggH,
    const float* __restrict__ W1, const float* __restrict__ b1,
    const float* __restrict__ epsp, float* __restrict__ h1,
    float* __restrict__ partial, int N)
{
    __shared__ float sW1[NF * H1D];
    __shared__ float sb1[H1D];
    __shared__ float sred[4][H1D], qred[4][H1D];
    int t = threadIdx.x;
    for (int i = t; i < NF * H1D; i += 256) sW1[i] = W1[i];
    if (t < H1D) sb1[t] = b1[t];
    __syncthreads();

    int i = blockIdx.x * 256 + t;
    bool active = i < N;
    float onep = 1.0f + epsp[0];
    int w = t >> 6;

    float acc[H1D];
    if (active) {
        float h0[NF];
        const float4* xs = reinterpret_cast<const float4*>(x + (size_t)i * NF);
        const float4* aL = reinterpret_cast<const float4*>(aggL + (size_t)i * NF);
        const float4* aH = aggH ? reinterpret_cast<const float4*>(aggH + (size_t)i * NF) : nullptr;
#pragma unroll
        for (int j = 0; j < 4; ++j) {
            float4 xv = xs[j], av = aL[j];
            float4 bv = aH ? aH[j] : make_float4(0.f, 0.f, 0.f, 0.f);
            h0[4 * j + 0] = onep * xv.x + av.x + bv.x;
            h0[4 * j + 1] = onep * xv.y + av.y + bv.y;
            h0[4 * j + 2] = onep * xv.z + av.z + bv.z;
            h0[4 * j + 3] = onep * xv.w + av.w + bv.w;
        }
#pragma unroll
        for (int j = 0; j < H1D; ++j) acc[j] = sb1[j];
#pragma unroll
        for (int k = 0; k < NF; ++k) {
            float a = h0[k];
#pragma unroll
            for (int j = 0; j < H1D; ++j) acc[j] += a * sW1[k * H1D + j];
        }
        float4* o = reinterpret_cast<float4*>(h1 + (size_t)i * H1D);
#pragma unroll
        for (int j = 0; j < 8; ++j)
            o[j] = make_float4(acc[4 * j + 0], acc[4 * j + 1], acc[4 * j + 2], acc[4 * j + 3]);
    } else {
#pragma unroll
        for (int j = 0; j < H1D; ++j) acc[j] = 0.0f;
    }

#pragma unroll
    for (int j = 0; j < H1D; ++j) {
        float s = acc[j];
        float q = s * s;
#pragma unroll
        for (int off = 32; off; off >>= 1) {
            s += __shfl_xor(s, off);
            q += __shfl_xor(q, off);
        }
        if ((t & 63) == 0) { sred[w][j] = s; qred[w][j] = q; }
    }
    __syncthreads();
    float* pb = partial + (size_t)blockIdx.x * 64;
    if (t < H1D)
        pb[t] = sred[0][t] + sred[1][t] + sred[2][t] + sred[3][t];
    else if (t < 64)
        pb[t] = qred[0][t - 32] + qred[1][t - 32] + qred[2][t - 32] + qred[3][t - 32];
}

__global__ __launch_bounds__(256) void k_red(
    const float* __restrict__ partial, int rows,
    const float* __restrict__ g, const float* __restrict__ bt,
    float* __restrict__ stats, int N)
{
    __shared__ float acc[4][64];
    int t = threadIdx.x;
    int c = t & 63, r0 = t >> 6;
    float s = 0.0f;
    for (int r = r0; r < rows; r += 4) s += partial[(size_t)r * 64 + c];
    acc[r0][c] = s;
    __syncthreads();
    if (t < 64) acc[0][t] = acc[0][t] + acc[1][t] + acc[2][t] + acc[3][t];
    __syncthreads();
    if (t < 32) {
        float sum = acc[0][t], sq = acc[0][32 + t];
        float mu = sum / (float)N;
        float var = sq / (float)N - mu * mu;
        float inv = rsqrtf(var + 1e-5f);
        float scale = g[t] * inv;
        float shift = bt[t] - mu * scale;
        stats[t] = scale;
        stats[32 + t] = shift;
    }
}

__global__ __launch_bounds__(256) void k_nodeB(
    const float* __restrict__ h1, const float* __restrict__ st1,
    const float* __restrict__ W2, const float* __restrict__ b2,
    float* __restrict__ h2, float* __restrict__ partial, int N)
{
    __shared__ float sW2[H1D * H2D];
    __shared__ float sb2[H2D], ssc[H1D], ssh[H1D];
    __shared__ float sred[4][H2D], qred[4][H2D];
    int t = threadIdx.x;
    for (int i = t; i < H1D * H2D; i += 256) sW2[i] = W2[i];
    if (t < H2D) sb2[t] = b2[t];
    if (t < H1D) { ssc[t] = st1[t]; ssh[t] = st1[H1D + t]; }
    __syncthreads();

    int i = blockIdx.x * 256 + t;
    bool active = i < N;
    int w = t >> 6;

    float acc[H2D];
    if (active) {
        float tg[H1D];
        const float4* hs = reinterpret_cast<const float4*>(h1 + (size_t)i * H1D);
#pragma unroll
        for (int j = 0; j < 8; ++j) {
            float4 v = hs[j];
            tg[4 * j + 0] = gelu_exact(v.x * ssc[4 * j + 0] + ssh[4 * j + 0]);
            tg[4 * j + 1] = gelu_exact(v.y * ssc[4 * j + 1] + ssh[4 * j + 1]);
            tg[4 * j + 2] = gelu_exact(v.z * ssc[4 * j + 2] + ssh[4 * j + 2]);
            tg[4 * j + 3] = gelu_exact(v.w * ssc[4 * j + 3] + ssh[4 * j + 3]);
        }
#pragma unroll
        for (int j = 0; j < H2D; ++j) acc[j] = sb2[j];
#pragma unroll
        for (int k = 0; k < H1D; ++k) {
            float a = tg[k];
#pragma unroll
            for (int j = 0; j < H2D; ++j) acc[j] += a * sW2[k * H2D + j];
        }
        float4* o = reinterpret_cast<float4*>(h2 + (size_t)i * H2D);
#pragma unroll
        for (int j = 0; j < 8; ++j)
            o[j] = make_float4(acc[4 * j + 0], acc[4 * j + 1], acc[4 * j + 2], acc[4 * j + 3]);
    } else {
#pragma unroll
        for (int j = 0; j < H2D; ++j) acc[j] = 0.0f;
    }

#pragma unroll
    for (int j = 0; j < H2D; ++j) {
        float s = acc[j];
        float q = s * s;
#pragma unroll
        for (int off = 32; off; off >>= 1) {
            s += __shfl_xor(s, off);
            q += __shfl_xor(q, off);
        }
        if ((t & 63) == 0) { sred[w][j] = s; qred[w][j] = q; }
    }
    __syncthreads();
    float* pb = partial + (size_t)blockIdx.x * 64;
    if (t < H2D)
        pb[t] = sred[0][t] + sred[1][t] + sred[2][t] + sred[3][t];
    else if (t < 64)
        pb[t] = qred[0][t - 32] + qred[1][t - 32] + qred[2][t - 32] + qred[3][t - 32];
}

__global__ __launch_bounds__(256) void k_nodeC(
    const float* __restrict__ h2, const float* __restrict__ st2,
    const float* __restrict__ W3, const float* __restrict__ b3,
    float* __restrict__ out, int N)
{
    __shared__ float sW3[H2D * OD];
    __shared__ float sb3[OD], ssc[H2D], ssh[H2D];
    int t = threadIdx.x;
    for (int i = t; i < H2D * OD; i += 256) sW3[i] = W3[i];
    if (t < OD) sb3[t] = b3[t];
    if (t < H2D) { ssc[t] = st2[t]; ssh[t] = st2[H2D + t]; }
    __syncthreads();

    int i = blockIdx.x * 256 + t;
    if (i >= N) return;

    float tg[H2D];
    const float4* hs = reinterpret_cast<const float4*>(h2 + (size_t)i * H2D);
#pragma unroll
    for (int j = 0; j < 8; ++j) {
        float4 v = hs[j];
        tg[4 * j + 0] = gelu_exact(v.x * ssc[4 * j + 0] + ssh[4 * j + 0]);
        tg[4 * j + 1] = gelu_exact(v.y * ssc[4 * j + 1] + ssh[4 * j + 1]);
        tg[4 * j + 2] = gelu_exact(v.z * ssc[4 * j + 2] + ssh[4 * j + 2]);
        tg[4 * j + 3] = gelu_exact(v.w * ssc[4 * j + 3] + ssh[4 * j + 3]);
    }
    float acc[OD];
#pragma unroll
    for (int j = 0; j < OD; ++j) acc[j] = sb3[j];
#pragma unroll
    for (int k = 0; k < H2D; ++k) {
        float a = tg[k];
#pragma unroll
        for (int j = 0; j < OD; ++j) acc[j] += a * sW3[k * OD + j];
    }
    float4* o = reinterpret_cast<float4*>(out + (size_t)i * OD);
#pragma unroll
    for (int j = 0; j < 16; ++j)
        o[j] = make_float4(acc[4 * j + 0], acc[4 * j + 1], acc[4 * j + 2], acc[4 * j + 3]);
}

extern "C" void kernel_launch(void* const* d_in, const int* in_sizes, int n_in,
                              void* d_out, int out_size, void* d_ws, size_t ws_size,
                              hipStream_t stream) {
    const float* x   = (const float*)d_in[0];
    const int*   ei  = (const int*)d_in[1];
    const float* ea  = (const float*)d_in[2];
    const float* We  = (const float*)d_in[3];
    const float* be  = (const float*)d_in[4];
    const float* W1  = (const float*)d_in[5];
    const float* b1  = (const float*)d_in[6];
    const float* g1  = (const float*)d_in[7];
    const float* bt1 = (const float*)d_in[8];
    const float* W2  = (const float*)d_in[9];
    const float* b2  = (const float*)d_in[10];
    const float* epsp= (const float*)d_in[11];
    const float* g2  = (const float*)d_in[12];
    const float* bt2 = (const float*)d_in[13];
    const float* W3  = (const float*)d_in[14];
    const float* b3  = (const float*)d_in[15];

    int N = in_sizes[0] / NF;
    int E = in_sizes[2] / EF;
    float* out = (float*)d_out;

    int ebl = (E + 255) / 256;
    int nbl = (N + 255) / 256;
    int gbl = (N + 3) / 4;
    int NBIN = (N + BNODE - 1) / BNODE;
    int per  = (E + PB - 1) / PB;

    auto al = [](size_t v) { return (v + 63) & ~(size_t)63; };

    char* ws = (char*)d_ws;
    size_t aggB   = al((size_t)N * NF * sizeof(float));
    size_t agg2B  = al((size_t)2 * N * NF * sizeof(float));
    size_t hB     = al((size_t)N * H1D * sizeof(float));
    size_t eB     = al((size_t)E * sizeof(int));
    size_t ea8B   = al((size_t)E * EF * sizeof(float));
    size_t msgB   = al((size_t)E * NF * sizeof(float));
    size_t cntMB  = al((size_t)PB * NBIN * sizeof(int));
    size_t ctB    = al((size_t)(NBIN + 1) * sizeof(int));
    size_t cntB   = al((size_t)N * sizeof(int));
    size_t rpB    = al((size_t)(N + 1) * sizeof(int));
    size_t statB  = al(512);
    size_t partB  = al((size_t)nbl * 64 * sizeof(float));

    size_t binTotal = ea8B + eB + agg2B + 2 * hB + 2 * cntMB + 2 * ctB + statB + 2 * partB;
    size_t msgTotal = msgB + eB + aggB + 2 * hB + cntB + rpB + statB + 2 * partB;

    bool binOK = (N < (1 << 24)) && (NBIN >= 1) && (NBIN <= 16000) &&
                 ((size_t)NBIN * 4 <= 64 * 1024) && (ws_size >= binTotal);

    if (binOK) {
        // ---- bin path ----
        char* p = ws;
        float* ea8    = (float*)p;    p += ea8B;
        unsigned* srcpk = (unsigned*)p; p += eB;
        float* agg2   = (float*)p;    p += agg2B;
        float* h1     = (float*)p;    p += hB;
        float* h2     = (float*)p;    p += hB;
        int*   cntM   = (int*)p;      p += cntMB;
        int*   offM   = (int*)p;      p += cntMB;
        int*   coltot = (int*)p;      p += ctB;
        int*   binbase= (int*)p;      p += ctB;
        float* stats1 = (float*)p;    p += statB;
        float* stats2 = stats1 + 64;
        float* part1  = (float*)p;    p += partB;
        float* part2  = (float*)p;    p += partB;

        size_t ldsHist = (size_t)NBIN * sizeof(int);
        k_count <<<PB, 256, ldsHist, stream>>>(ei, cntM, N, E, NBIN, per);
        k_mscan <<<NBIN, 256, 0, stream>>>(cntM, offM, coltot, NBIN);
        k_scan  <<<1, SCAN_T, 0, stream>>>(coltot, binbase, NBIN);
        k_place <<<PB, 256, ldsHist, stream>>>(ei, ea, offM, binbase, srcpk, ea8, N, E, NBIN, per);
        k_binagg<<<NBIN * 2, 256, 0, stream>>>(x, srcpk, ea8, We, be, binbase, agg2, N);
        k_nodeA <<<nbl, 256, 0, stream>>>(x, agg2, agg2 + (size_t)N * NF, W1, b1, epsp, h1, part1, N);
        k_red   <<<1, 256, 0, stream>>>(part1, nbl, g1, bt1, stats1, N);
        k_nodeB <<<nbl, 256, 0, stream>>>(h1, stats1, W2, b2, h2, part2, N);
        k_red   <<<1, 256, 0, stream>>>(part2, nbl, g2, bt2, stats2, N);
        k_nodeC <<<nbl, 256, 0, stream>>>(h2, stats2, W3, b3, out, N);
    } else if (ws_size >= msgTotal) {
        // ---- msg-tier fallback (round-7 proven structure) ----
        char* p = ws;
        float* msg    = (float*)p;    p += msgB;
        unsigned* packed = (unsigned*)p; p += eB;
        float* agg    = (float*)p;    p += aggB;
        float* h1     = (float*)p;    p += hB;
        float* h2     = (float*)p;    p += hB;
        int*   count  = (int*)p;      p += cntB;
        int*   rowptr = (int*)p;      p += rpB;
        float* stats1 = (float*)p;    p += statB;
        float* stats2 = stats1 + 64;
        float* part1  = (float*)p;    p += partB;
        float* part2  = (float*)p;    p += partB;

        hipMemsetAsync(count, 0, (size_t)N * sizeof(int), stream);
        k_histp   <<<ebl, 256, 0, stream>>>(ei, count, packed, N, E);
        k_scan    <<<1, SCAN_T, 0, stream>>>(count, rowptr, N);
        k_scatmsg <<<ebl, 256, 0, stream>>>(x, ei, ea, We, be, rowptr, packed, msg, N, E);
        k_gatherseq<<<gbl, 256, 0, stream>>>(rowptr, msg, agg, N);
        k_nodeA   <<<nbl, 256, 0, stream>>>(x, agg, nullptr, W1, b1, epsp, h1, part1, N);
        k_red     <<<1, 256, 0, stream>>>(part1, nbl, g1, bt1, stats1, N);
        k_nodeB   <<<nbl, 256, 0, stream>>>(h1, stats1, W2, b2, h2, part2, N);
        k_red     <<<1, 256, 0, stream>>>(part2, nbl, g2, bt2, stats2, N);
        k_nodeC   <<<nbl, 256, 0, stream>>>(h2, stats2, W3, b3, out, N);
    } else {
        // ---- tier C: atomic scatter ----
        char* p = ws;
        float* agg = (float*)p; p += aggB;
        float* h1  = (float*)p; p += hB;
        float* h2  = (float*)p; p += hB;
        float* stats1 = (float*)p; p += statB;
        float* stats2 = stats1 + 64;
        float* part1  = (float*)p; p += partB;
        float* part2  = (float*)p; p += partB;

        hipMemsetAsync(agg, 0, (size_t)N * NF * sizeof(float), stream);
        k_edge  <<<ebl, 256, 0, stream>>>(x, ei, ea, We, be, agg, N, E);
        k_nodeA <<<nbl, 256, 0, stream>>>(x, agg, nullptr, W1, b1, epsp, h1, part1, N);
        k_red   <<<1, 256, 0, stream>>>(part1, nbl, g1, bt1, stats1, N);
        k_nodeB <<<nbl, 256, 0, stream>>>(h1, stats1, W2, b2, h2, part2, N);
        k_red   <<<1, 256, 0, stream>>>(part2, nbl, g2, bt2, stats2, N);
        k_nodeC <<<nbl, 256, 0, stream>>>(h2, stats2, W3, b3, out, N);
    }
}